// Round 12
// baseline (81.439 us; speedup 1.0000x reference)
//
#include <hip/hip_runtime.h>

#define N_NODES 10000
#define N_PAD   10112          // multiple of 128 for BM=128 tiles
#define N_EDGES 160000
#define DIM     512
#define KDIM    1024           // concatenated K = [h | neigh]
#define CAP     64             // per-node edge bucket capacity (max deg ~35)

#define BM 128
#define BN 128
#define BK 64
#define KITERS (KDIM / BK)     // 16

typedef __attribute__((ext_vector_type(8))) short bf16x8;
typedef __attribute__((ext_vector_type(4))) float f32x4;
typedef __attribute__((ext_vector_type(2))) float f32x2;

static __device__ __forceinline__ ushort f2bf(float f) {
    union { float f; unsigned u; } x; x.f = f;
    unsigned u = x.u + 0x7fff + ((x.u >> 16) & 1);   // round-to-nearest-even
    return (ushort)(u >> 16);
}
static __device__ __forceinline__ float b2f(ushort u) {
    union { unsigned u; float f; } x; x.u = ((unsigned)u) << 16; return x.f;
}

// ---------------------------------------------------------------------------
// conv_w: Wc[c][k] = bf16([Wself | Wneigh]); also zeroes cnt (runs first).
// ---------------------------------------------------------------------------
__global__ __launch_bounds__(256) void conv_w(
    const float* __restrict__ Wself, const float* __restrict__ Wneigh,
    ushort* __restrict__ Wc, int* __restrict__ cnt)
{
    int idx = blockIdx.x * 256 + threadIdx.x;     // over 512*128 = 65536
    if (idx < N_NODES) cnt[idx] = 0;
    int c  = idx >> 7;
    int k8 = idx & 127;
    const float* src = (k8 < 64) ? (Wself + (size_t)c * DIM + k8 * 8)
                                 : (Wneigh + (size_t)c * DIM + (k8 - 64) * 8);
    float4 v0 = *(const float4*)src;
    float4 v1 = *(const float4*)(src + 4);
    ushort* dst = Wc + (size_t)c * KDIM + k8 * 8;
    ushort4 o0 = { f2bf(v0.x), f2bf(v0.y), f2bf(v0.z), f2bf(v0.w) };
    ushort4 o1 = { f2bf(v1.x), f2bf(v1.y), f2bf(v1.z), f2bf(v1.w) };
    *(ushort4*)dst = o0;
    *(ushort4*)(dst + 4) = o1;
}

// ---------------------------------------------------------------------------
// conv_x: left half of X = bf16(h) AND H8 = fp8(h) (HW packed cvt);
// pad rows zeroed.  First N_EDGES threads also bucket edges.
// ---------------------------------------------------------------------------
__global__ __launch_bounds__(256) void conv_x(
    const float* __restrict__ h, ushort* __restrict__ X,
    unsigned char* __restrict__ H8,
    const int* __restrict__ eidx, int* __restrict__ cnt, int* __restrict__ col)
{
    int idx = blockIdx.x * 256 + threadIdx.x;
    if (idx < N_EDGES) {
        int s = eidx[idx];
        int d = eidx[N_EDGES + idx];
        int p = atomicAdd(&cnt[s], 1);
        if (p < CAP) col[(s << 6) + p] = d;
    }
    int n  = idx >> 7;
    int k8 = idx & 127;
    if (n >= N_PAD) return;
    ushort* dst = X + (size_t)n * KDIM + k8 * 8;
    if (n >= N_NODES) {                      // zero pad row (full 1024)
        ushort4 z = {0, 0, 0, 0};
        *(ushort4*)dst = z;
        *(ushort4*)(dst + 4) = z;
        return;
    }
    if (k8 >= 64) return;                    // right half written by gather
    const float* src = h + (size_t)n * DIM + k8 * 8;
    float4 v0 = *(const float4*)src;
    float4 v1 = *(const float4*)(src + 4);
    ushort4 o0 = { f2bf(v0.x), f2bf(v0.y), f2bf(v0.z), f2bf(v0.w) };
    ushort4 o1 = { f2bf(v1.x), f2bf(v1.y), f2bf(v1.z), f2bf(v1.w) };
    *(ushort4*)dst = o0;
    *(ushort4*)(dst + 4) = o1;
    // fp8 copy for the gather, HW packed converts (2 f32 -> 1 instr)
    uint2 p8;
    int r0 = 0, r1 = 0;
    r0 = __builtin_amdgcn_cvt_pk_fp8_f32(v0.x, v0.y, r0, false);
    r0 = __builtin_amdgcn_cvt_pk_fp8_f32(v0.z, v0.w, r0, true);
    r1 = __builtin_amdgcn_cvt_pk_fp8_f32(v1.x, v1.y, r1, false);
    r1 = __builtin_amdgcn_cvt_pk_fp8_f32(v1.z, v1.w, r1, true);
    p8.x = (unsigned)r0;
    p8.y = (unsigned)r1;
    *(uint2*)(H8 + (size_t)n * DIM + k8 * 8) = p8;
}

// ---------------------------------------------------------------------------
// Gather-aggregate (fp8 source, HW decode): one wave per node; lane owns
// cols lane*8..+7 (8 B/edge).  Bucketed edges broadcast via shfl; unroll x8.
// ---------------------------------------------------------------------------
__global__ __launch_bounds__(256) void gather_agg(
    const int* __restrict__ cnt, const int* __restrict__ col,
    const unsigned char* __restrict__ H8,
    ushort* __restrict__ X, float* __restrict__ deg)
{
    int gid  = blockIdx.x * 256 + threadIdx.x;
    int n    = gid >> 6;
    int lane = gid & 63;
    if (n >= N_NODES) return;
    int d  = cnt[n];
    int nk = d < CAP ? d : CAP;

    int myc = (lane < nk) ? col[(n << 6) + lane] : 0;

    f32x2 a01 = {0.f, 0.f}, a23 = {0.f, 0.f}, a45 = {0.f, 0.f}, a67 = {0.f, 0.f};
    int k = 0;
    for (; k + 8 <= nk; k += 8) {
        uint2 v[8];
#pragma unroll
        for (int u = 0; u < 8; ++u) {
            int dst = __shfl(myc, k + u);
            v[u] = *(const uint2*)(H8 + (size_t)dst * DIM + lane * 8);
        }
#pragma unroll
        for (int u = 0; u < 8; ++u) {
            f32x2 d01 = __builtin_amdgcn_cvt_pk_f32_fp8((int)v[u].x, false);
            f32x2 d23 = __builtin_amdgcn_cvt_pk_f32_fp8((int)v[u].x, true);
            f32x2 d45 = __builtin_amdgcn_cvt_pk_f32_fp8((int)v[u].y, false);
            f32x2 d67 = __builtin_amdgcn_cvt_pk_f32_fp8((int)v[u].y, true);
            a01 += d01; a23 += d23; a45 += d45; a67 += d67;
        }
    }
    for (; k < nk; ++k) {
        int dst = __shfl(myc, k);
        uint2 v = *(const uint2*)(H8 + (size_t)dst * DIM + lane * 8);
        a01 += __builtin_amdgcn_cvt_pk_f32_fp8((int)v.x, false);
        a23 += __builtin_amdgcn_cvt_pk_f32_fp8((int)v.x, true);
        a45 += __builtin_amdgcn_cvt_pk_f32_fp8((int)v.y, false);
        a67 += __builtin_amdgcn_cvt_pk_f32_fp8((int)v.y, true);
    }
    float inv = 1.0f / fmaxf((float)d, 1.0f);
    ushort* xr = X + (size_t)n * KDIM + DIM + lane * 8;
    ushort4 o0 = { f2bf(a01[0] * inv), f2bf(a01[1] * inv),
                   f2bf(a23[0] * inv), f2bf(a23[1] * inv) };
    ushort4 o1 = { f2bf(a45[0] * inv), f2bf(a45[1] * inv),
                   f2bf(a67[0] * inv), f2bf(a67[1] * inv) };
    *(ushort4*)xr       = o0;
    *(ushort4*)(xr + 4) = o1;
    if (lane == 0) deg[n] = (float)d;
}

// ---------------------------------------------------------------------------
// MFMA GEMM: 128x128 tile (65 FLOP/staged-byte vs 43 at 64x128), 256 thr /
// 4 waves (2x2), wave tile 64x64, acc 4x4.  global_load_lds(16B) staging,
// XOR-swizzled source, dbuf, 1 barrier/K-step.  Grid (col, row).
// ---------------------------------------------------------------------------
#define MFMA(A, B, C) __builtin_amdgcn_mfma_f32_16x16x32_bf16(A, B, C, 0, 0, 0)

__global__ __launch_bounds__(256) void mfma_gemm(
    const ushort* __restrict__ X, const ushort* __restrict__ Wc,
    const float* __restrict__ deg,
    const float* __restrict__ bself, const float* __restrict__ bneigh,
    ushort* __restrict__ Y)
{
    __shared__ ushort As[2][BM * BK];    // 2 x 16 KB, linear (DMA dest)
    __shared__ ushort Bs[2][BN * BK];    // 2 x 16 KB

    const int t    = threadIdx.x;
    const int lane = t & 63;
    const int wave = t >> 6;
    const int row0 = blockIdx.y * BM;
    const int col0 = blockIdx.x * BN;
    const int wr   = (wave >> 1) * 64;   // wave row offset in tile
    const int wc   = (wave & 1) * 64;    // wave col offset in tile
    const int fr   = lane & 15;
    const int fq   = lane >> 4;          // 0..3

#define STAGE(BUF, IT)                                                         \
    {                                                                          \
        const int k0s = (IT) * BK;                                             \
        _Pragma("unroll")                                                      \
        for (int s = 0; s < 4; ++s) {                                          \
            int c = t + s * 256;                                               \
            int row = c >> 3;                                                  \
            int ks = k0s + (((c & 7) ^ (row & 7)) << 3);                       \
            __builtin_amdgcn_global_load_lds(                                  \
                (const __attribute__((address_space(1))) void*)                \
                    (X + (size_t)(row0 + row) * KDIM + ks),                    \
                (__attribute__((address_space(3))) void*)(&As[BUF][c * 8]),    \
                16, 0, 0);                                                     \
        }                                                                      \
        _Pragma("unroll")                                                      \
        for (int s = 0; s < 4; ++s) {                                          \
            int c = t + s * 256;                                               \
            int row = c >> 3;                                                  \
            int ks = k0s + (((c & 7) ^ (row & 7)) << 3);                       \
            __builtin_amdgcn_global_load_lds(                                  \
                (const __attribute__((address_space(1))) void*)                \
                    (Wc + (size_t)(col0 + row) * KDIM + ks),                   \
                (__attribute__((address_space(3))) void*)(&Bs[BUF][c * 8]),    \
                16, 0, 0);                                                     \
        }                                                                      \
    }

    f32x4 acc[4][4];
#pragma unroll
    for (int i = 0; i < 4; ++i)
#pragma unroll
        for (int j = 0; j < 4; ++j) acc[i][j] = (f32x4){0.f, 0.f, 0.f, 0.f};

    STAGE(0, 0);
    __syncthreads();                     // drains vmcnt(0) + barrier

    int buf = 0;
    for (int it = 0; it < KITERS; ++it) {
        if (it + 1 < KITERS) STAGE(buf ^ 1, it + 1);   // async, overlaps MFMAs

        const ushort* as = As[buf];
        const ushort* bs = Bs[buf];
#pragma unroll
        for (int inner = 0; inner < 2; ++inner) {
            const int sw = (((inner * 4 + fq) ^ (fr & 7)) << 3);  // swizzled k-off
            bf16x8 a[4], b[4];
#pragma unroll
            for (int i = 0; i < 4; ++i)
                a[i] = *(const bf16x8*)(as + (wr + i * 16 + fr) * BK + sw);
#pragma unroll
            for (int j = 0; j < 4; ++j)
                b[j] = *(const bf16x8*)(bs + (wc + j * 16 + fr) * BK + sw);
#pragma unroll
            for (int i = 0; i < 4; ++i)
#pragma unroll
                for (int j = 0; j < 4; ++j)
                    acc[i][j] = MFMA(a[i], b[j], acc[i][j]);
        }
        __syncthreads();                 // next-tile DMA drained; reads done
        buf ^= 1;
    }

    // epilogue: Y = bf16( relu(acc + bself + (deg>0)*bneigh) )
#pragma unroll
    for (int i = 0; i < 4; ++i) {
#pragma unroll
        for (int r = 0; r < 4; ++r) {
            int gr = row0 + wr + i * 16 + fq * 4 + r;
            float hb = (gr < N_NODES && deg[gr] > 0.0f) ? 1.0f : 0.0f;
            ushort* yrow = Y + (size_t)gr * DIM;
#pragma unroll
            for (int j = 0; j < 4; ++j) {
                int gc = col0 + wc + j * 16 + fr;
                float v = fmaxf(acc[i][j][r] + bself[gc] + hb * bneigh[gc], 0.f);
                yrow[gc] = f2bf(v);
            }
        }
    }
}

// ---------------------------------------------------------------------------
// LayerNorm: out = LN(h + Y), one 256-thread block per node row.
// ---------------------------------------------------------------------------
__global__ __launch_bounds__(256) void ln_kernel(
    const ushort* __restrict__ Y, const float* __restrict__ h,
    const float* __restrict__ g, const float* __restrict__ b,
    float* __restrict__ out)
{
    __shared__ float red[8];
    int n = blockIdx.x;
    int t = threadIdx.x;
    float2 hv = *(const float2*)(h + (size_t)n * DIM + t * 2);
    ushort2 yv = *(const ushort2*)(Y + (size_t)n * DIM + t * 2);
    float v0 = hv.x + b2f(yv.x);
    float v1 = hv.y + b2f(yv.y);
    float s  = v0 + v1;
    float sq = v0 * v0 + v1 * v1;
#pragma unroll
    for (int off = 32; off >= 1; off >>= 1) {
        s  += __shfl_xor(s, off);
        sq += __shfl_xor(sq, off);
    }
    int wave = t >> 6;
    if ((t & 63) == 0) { red[wave] = s; red[4 + wave] = sq; }
    __syncthreads();
    s  = red[0] + red[1] + red[2] + red[3];
    sq = red[4] + red[5] + red[6] + red[7];
    float mean = s * (1.0f / DIM);
    float var  = sq * (1.0f / DIM) - mean * mean;
    float rstd = rsqrtf(var + 1e-5f);
    float2 gv = *(const float2*)(g + t * 2);
    float2 bv = *(const float2*)(b + t * 2);
    float2 o;
    o.x = (v0 - mean) * rstd * gv.x + bv.x;
    o.y = (v1 - mean) * rstd * gv.y + bv.y;
    *(float2*)(out + (size_t)n * DIM + t * 2) = o;
}

// ---------------------------------------------------------------------------
extern "C" void kernel_launch(void* const* d_in, const int* in_sizes, int n_in,
                              void* d_out, int out_size, void* d_ws, size_t ws_size,
                              hipStream_t stream)
{
    const float* h      = (const float*)d_in[0];
    const int*   eidx   = (const int*)d_in[1];
    const float* Wself  = (const float*)d_in[2];
    const float* bself  = (const float*)d_in[3];
    const float* Wneigh = (const float*)d_in[4];
    const float* bneigh = (const float*)d_in[5];
    const float* gamma  = (const float*)d_in[6];
    const float* beta   = (const float*)d_in[7];
    float* out = (float*)d_out;

    // ws layout: X (20.7MB) | Wc (1MB) | Y (10.4MB) | deg | cnt | col | H8 (5.1MB)
    ushort* X   = (ushort*)d_ws;                          // N_PAD*KDIM bf16
    ushort* Wc  = X + (size_t)N_PAD * KDIM;               // 512*KDIM bf16
    ushort* Y   = Wc + (size_t)DIM * KDIM;                // N_PAD*DIM bf16
    float* deg  = (float*)(Y + (size_t)N_PAD * DIM);      // N f32
    int* cnt    = (int*)(deg + N_NODES);                  // N int
    int* col    = cnt + N_NODES;                          // N*CAP int (2.56MB)
    unsigned char* H8 = (unsigned char*)(col + (size_t)N_NODES * CAP);  // N*DIM fp8

    conv_w<<<(DIM * 128) / 256, 256, 0, stream>>>(Wself, Wneigh, Wc, cnt);
    conv_x<<<(N_PAD * 128) / 256, 256, 0, stream>>>(h, X, H8, eidx, cnt, col);
    gather_agg<<<(N_NODES * 64) / 256, 256, 0, stream>>>(cnt, col, H8, X, deg);

    dim3 gg(DIM / BN, N_PAD / BM);    // (4, 79) = 316 blocks
    mfma_gemm<<<gg, 256, 0, stream>>>(X, Wc, deg, bself, bneigh, Y);

    ln_kernel<<<N_NODES, 256, 0, stream>>>(Y, h, gamma, beta, out);
}

// Round 13
// 71.459 us; speedup vs baseline: 1.1397x; 1.1397x over previous
//
#include <hip/hip_runtime.h>

#define N_NODES 10000
#define N_PAD   10048          // multiple of 64 for BM=64 tiles
#define N_EDGES 160000
#define DIM     512
#define KDIM    1024           // concatenated K = [h | neigh]
#define CAP     64             // per-node edge bucket capacity (max deg ~35)

#define BM 64
#define BN 128
#define BK 64
#define KITERS (KDIM / BK)     // 16
#define NWG    ((N_PAD / BM) * (DIM / BN))   // 628
#define SWZ_Q  (NWG / 8)                     // 78
#define SWZ_R  (NWG % 8)                     // 4

typedef __attribute__((ext_vector_type(8))) short bf16x8;
typedef __attribute__((ext_vector_type(4))) float f32x4;
typedef __attribute__((ext_vector_type(2))) float f32x2;

static __device__ __forceinline__ ushort f2bf(float f) {
    union { float f; unsigned u; } x; x.f = f;
    unsigned u = x.u + 0x7fff + ((x.u >> 16) & 1);   // round-to-nearest-even
    return (ushort)(u >> 16);
}
static __device__ __forceinline__ float b2f(ushort u) {
    union { unsigned u; float f; } x; x.u = ((unsigned)u) << 16; return x.f;
}

// ---------------------------------------------------------------------------
// conv_w: Wc[c][k] = bf16([Wself | Wneigh]); also zeroes cnt (runs first).
// ---------------------------------------------------------------------------
__global__ __launch_bounds__(256) void conv_w(
    const float* __restrict__ Wself, const float* __restrict__ Wneigh,
    ushort* __restrict__ Wc, int* __restrict__ cnt)
{
    int idx = blockIdx.x * 256 + threadIdx.x;     // over 512*128 = 65536
    if (idx < N_NODES) cnt[idx] = 0;
    int c  = idx >> 7;
    int k8 = idx & 127;
    const float* src = (k8 < 64) ? (Wself + (size_t)c * DIM + k8 * 8)
                                 : (Wneigh + (size_t)c * DIM + (k8 - 64) * 8);
    float4 v0 = *(const float4*)src;
    float4 v1 = *(const float4*)(src + 4);
    ushort* dst = Wc + (size_t)c * KDIM + k8 * 8;
    ushort4 o0 = { f2bf(v0.x), f2bf(v0.y), f2bf(v0.z), f2bf(v0.w) };
    ushort4 o1 = { f2bf(v1.x), f2bf(v1.y), f2bf(v1.z), f2bf(v1.w) };
    *(ushort4*)dst = o0;
    *(ushort4*)(dst + 4) = o1;
}

// ---------------------------------------------------------------------------
// conv_x: left half of X = bf16(h) AND H8 = fp8(h) (HW packed cvt);
// pad rows zeroed.  First N_EDGES threads also bucket edges.
// ---------------------------------------------------------------------------
__global__ __launch_bounds__(256) void conv_x(
    const float* __restrict__ h, ushort* __restrict__ X,
    unsigned char* __restrict__ H8,
    const int* __restrict__ eidx, int* __restrict__ cnt, int* __restrict__ col)
{
    int idx = blockIdx.x * 256 + threadIdx.x;
    if (idx < N_EDGES) {
        int s = eidx[idx];
        int d = eidx[N_EDGES + idx];
        int p = atomicAdd(&cnt[s], 1);
        if (p < CAP) col[(s << 6) + p] = d;
    }
    int n  = idx >> 7;
    int k8 = idx & 127;
    if (n >= N_PAD) return;
    ushort* dst = X + (size_t)n * KDIM + k8 * 8;
    if (n >= N_NODES) {                      // zero pad row (full 1024)
        ushort4 z = {0, 0, 0, 0};
        *(ushort4*)dst = z;
        *(ushort4*)(dst + 4) = z;
        return;
    }
    if (k8 >= 64) return;                    // right half written by gather
    const float* src = h + (size_t)n * DIM + k8 * 8;
    float4 v0 = *(const float4*)src;
    float4 v1 = *(const float4*)(src + 4);
    ushort4 o0 = { f2bf(v0.x), f2bf(v0.y), f2bf(v0.z), f2bf(v0.w) };
    ushort4 o1 = { f2bf(v1.x), f2bf(v1.y), f2bf(v1.z), f2bf(v1.w) };
    *(ushort4*)dst = o0;
    *(ushort4*)(dst + 4) = o1;
    // fp8 copy for the gather, HW packed converts (2 f32 -> 1 instr)
    uint2 p8;
    int r0 = 0, r1 = 0;
    r0 = __builtin_amdgcn_cvt_pk_fp8_f32(v0.x, v0.y, r0, false);
    r0 = __builtin_amdgcn_cvt_pk_fp8_f32(v0.z, v0.w, r0, true);
    r1 = __builtin_amdgcn_cvt_pk_fp8_f32(v1.x, v1.y, r1, false);
    r1 = __builtin_amdgcn_cvt_pk_fp8_f32(v1.z, v1.w, r1, true);
    p8.x = (unsigned)r0;
    p8.y = (unsigned)r1;
    *(uint2*)(H8 + (size_t)n * DIM + k8 * 8) = p8;
}

// ---------------------------------------------------------------------------
// Gather-aggregate (fp8 source, HW decode): one wave per node; lane owns
// cols lane*8..+7 (8 B/edge).  Bucketed edges broadcast via shfl; unroll x8.
// ---------------------------------------------------------------------------
__global__ __launch_bounds__(256) void gather_agg(
    const int* __restrict__ cnt, const int* __restrict__ col,
    const unsigned char* __restrict__ H8,
    ushort* __restrict__ X, float* __restrict__ deg)
{
    int gid  = blockIdx.x * 256 + threadIdx.x;
    int n    = gid >> 6;
    int lane = gid & 63;
    if (n >= N_NODES) return;
    int d  = cnt[n];
    int nk = d < CAP ? d : CAP;

    int myc = (lane < nk) ? col[(n << 6) + lane] : 0;

    f32x2 a01 = {0.f, 0.f}, a23 = {0.f, 0.f}, a45 = {0.f, 0.f}, a67 = {0.f, 0.f};
    int k = 0;
    for (; k + 8 <= nk; k += 8) {
        uint2 v[8];
#pragma unroll
        for (int u = 0; u < 8; ++u) {
            int dst = __shfl(myc, k + u);
            v[u] = *(const uint2*)(H8 + (size_t)dst * DIM + lane * 8);
        }
#pragma unroll
        for (int u = 0; u < 8; ++u) {
            a01 += __builtin_amdgcn_cvt_pk_f32_fp8((int)v[u].x, false);
            a23 += __builtin_amdgcn_cvt_pk_f32_fp8((int)v[u].x, true);
            a45 += __builtin_amdgcn_cvt_pk_f32_fp8((int)v[u].y, false);
            a67 += __builtin_amdgcn_cvt_pk_f32_fp8((int)v[u].y, true);
        }
    }
    for (; k < nk; ++k) {
        int dst = __shfl(myc, k);
        uint2 v = *(const uint2*)(H8 + (size_t)dst * DIM + lane * 8);
        a01 += __builtin_amdgcn_cvt_pk_f32_fp8((int)v.x, false);
        a23 += __builtin_amdgcn_cvt_pk_f32_fp8((int)v.x, true);
        a45 += __builtin_amdgcn_cvt_pk_f32_fp8((int)v.y, false);
        a67 += __builtin_amdgcn_cvt_pk_f32_fp8((int)v.y, true);
    }
    float inv = 1.0f / fmaxf((float)d, 1.0f);
    ushort* xr = X + (size_t)n * KDIM + DIM + lane * 8;
    ushort4 o0 = { f2bf(a01[0] * inv), f2bf(a01[1] * inv),
                   f2bf(a23[0] * inv), f2bf(a23[1] * inv) };
    ushort4 o1 = { f2bf(a45[0] * inv), f2bf(a45[1] * inv),
                   f2bf(a67[0] * inv), f2bf(a67[1] * inv) };
    *(ushort4*)xr       = o0;
    *(ushort4*)(xr + 4) = o1;
    if (lane == 0) deg[n] = (float)d;
}

// ---------------------------------------------------------------------------
// MFMA GEMM (R11-best config): 256 thr / 4 waves (2x2), tile 64x128,
// wave 32x64.  global_load_lds(16B) staging, XOR-swizzled source, dbuf,
// 1 barrier/K-step.  1-D grid with bijective XCD swizzle (m204): each XCD
// owns a contiguous chunk of ~20 row-groups x 4 col-blocks -> X slabs hit
// its private L2 once instead of 4 L2s refetching from L3.
// ---------------------------------------------------------------------------
#define MFMA(A, B, C) __builtin_amdgcn_mfma_f32_16x16x32_bf16(A, B, C, 0, 0, 0)

__global__ __launch_bounds__(256) void mfma_gemm(
    const ushort* __restrict__ X, const ushort* __restrict__ Wc,
    const float* __restrict__ deg,
    const float* __restrict__ bself, const float* __restrict__ bneigh,
    ushort* __restrict__ Y)
{
    __shared__ ushort As[2][BM * BK];    // 2 x  8 KB, linear (DMA dest)
    __shared__ ushort Bs[2][BN * BK];    // 2 x 16 KB

    // bijective XCD swizzle (NWG=628, Q=78, R=4)
    const int orig = blockIdx.x;
    const int xcd  = orig & 7;
    const int loc  = orig >> 3;
    const int wgid = (xcd < SWZ_R ? xcd * (SWZ_Q + 1)
                                  : SWZ_R * (SWZ_Q + 1) + (xcd - SWZ_R) * SWZ_Q) + loc;
    const int row0 = (wgid >> 2) * BM;   // 157 row-groups
    const int col0 = (wgid & 3) * BN;    // 4 col-blocks

    const int t    = threadIdx.x;
    const int lane = t & 63;
    const int wave = t >> 6;
    const int wr   = (wave >> 1) * 32;   // wave row offset in tile
    const int wc   = (wave & 1) * 64;    // wave col offset in tile
    const int fr   = lane & 15;
    const int fq   = lane >> 4;          // 0..3

#define STAGE(BUF, IT)                                                         \
    {                                                                          \
        const int k0s = (IT) * BK;                                             \
        _Pragma("unroll")                                                      \
        for (int s = 0; s < 2; ++s) {                                          \
            int c = t + s * 256;                                               \
            int row = c >> 3;                                                  \
            int ks = k0s + (((c & 7) ^ (row & 7)) << 3);                       \
            __builtin_amdgcn_global_load_lds(                                  \
                (const __attribute__((address_space(1))) void*)                \
                    (X + (size_t)(row0 + row) * KDIM + ks),                    \
                (__attribute__((address_space(3))) void*)(&As[BUF][c * 8]),    \
                16, 0, 0);                                                     \
        }                                                                      \
        _Pragma("unroll")                                                      \
        for (int s = 0; s < 4; ++s) {                                          \
            int c = t + s * 256;                                               \
            int row = c >> 3;                                                  \
            int ks = k0s + (((c & 7) ^ (row & 7)) << 3);                       \
            __builtin_amdgcn_global_load_lds(                                  \
                (const __attribute__((address_space(1))) void*)                \
                    (Wc + (size_t)(col0 + row) * KDIM + ks),                   \
                (__attribute__((address_space(3))) void*)(&Bs[BUF][c * 8]),    \
                16, 0, 0);                                                     \
        }                                                                      \
    }

    f32x4 acc[2][4];
#pragma unroll
    for (int i = 0; i < 2; ++i)
#pragma unroll
        for (int j = 0; j < 4; ++j) acc[i][j] = (f32x4){0.f, 0.f, 0.f, 0.f};

    STAGE(0, 0);
    __syncthreads();                     // drains vmcnt(0) + barrier

    int buf = 0;
    for (int it = 0; it < KITERS; ++it) {
        if (it + 1 < KITERS) STAGE(buf ^ 1, it + 1);   // async, overlaps MFMAs

        const ushort* as = As[buf];
        const ushort* bs = Bs[buf];
#pragma unroll
        for (int inner = 0; inner < 2; ++inner) {
            const int sw = (((inner * 4 + fq) ^ (fr & 7)) << 3);  // swizzled k-off
            bf16x8 a0 = *(const bf16x8*)(as + (wr + fr) * BK + sw);
            bf16x8 a1 = *(const bf16x8*)(as + (wr + 16 + fr) * BK + sw);
#pragma unroll
            for (int j = 0; j < 4; ++j) {
                bf16x8 bv = *(const bf16x8*)(bs + (wc + j * 16 + fr) * BK + sw);
                acc[0][j] = MFMA(a0, bv, acc[0][j]);
                acc[1][j] = MFMA(a1, bv, acc[1][j]);
            }
        }
        __syncthreads();                 // next-tile DMA drained; reads done
        buf ^= 1;
    }

    // epilogue: Y = bf16( relu(acc + bself + (deg>0)*bneigh) )
#pragma unroll
    for (int i = 0; i < 2; ++i) {
#pragma unroll
        for (int r = 0; r < 4; ++r) {
            int gr = row0 + wr + i * 16 + fq * 4 + r;
            float hb = (gr < N_NODES && deg[gr] > 0.0f) ? 1.0f : 0.0f;
            ushort* yrow = Y + (size_t)gr * DIM;
#pragma unroll
            for (int j = 0; j < 4; ++j) {
                int gc = col0 + wc + j * 16 + fr;
                float v = fmaxf(acc[i][j][r] + bself[gc] + hb * bneigh[gc], 0.f);
                yrow[gc] = f2bf(v);
            }
        }
    }
}

// ---------------------------------------------------------------------------
// LayerNorm: out = LN(h + Y), one 256-thread block per node row.
// ---------------------------------------------------------------------------
__global__ __launch_bounds__(256) void ln_kernel(
    const ushort* __restrict__ Y, const float* __restrict__ h,
    const float* __restrict__ g, const float* __restrict__ b,
    float* __restrict__ out)
{
    __shared__ float red[8];
    int n = blockIdx.x;
    int t = threadIdx.x;
    float2 hv = *(const float2*)(h + (size_t)n * DIM + t * 2);
    ushort2 yv = *(const ushort2*)(Y + (size_t)n * DIM + t * 2);
    float v0 = hv.x + b2f(yv.x);
    float v1 = hv.y + b2f(yv.y);
    float s  = v0 + v1;
    float sq = v0 * v0 + v1 * v1;
#pragma unroll
    for (int off = 32; off >= 1; off >>= 1) {
        s  += __shfl_xor(s, off);
        sq += __shfl_xor(sq, off);
    }
    int wave = t >> 6;
    if ((t & 63) == 0) { red[wave] = s; red[4 + wave] = sq; }
    __syncthreads();
    s  = red[0] + red[1] + red[2] + red[3];
    sq = red[4] + red[5] + red[6] + red[7];
    float mean = s * (1.0f / DIM);
    float var  = sq * (1.0f / DIM) - mean * mean;
    float rstd = rsqrtf(var + 1e-5f);
    float2 gv = *(const float2*)(g + t * 2);
    float2 bv = *(const float2*)(b + t * 2);
    float2 o;
    o.x = (v0 - mean) * rstd * gv.x + bv.x;
    o.y = (v1 - mean) * rstd * gv.y + bv.y;
    *(float2*)(out + (size_t)n * DIM + t * 2) = o;
}

// ---------------------------------------------------------------------------
extern "C" void kernel_launch(void* const* d_in, const int* in_sizes, int n_in,
                              void* d_out, int out_size, void* d_ws, size_t ws_size,
                              hipStream_t stream)
{
    const float* h      = (const float*)d_in[0];
    const int*   eidx   = (const int*)d_in[1];
    const float* Wself  = (const float*)d_in[2];
    const float* bself  = (const float*)d_in[3];
    const float* Wneigh = (const float*)d_in[4];
    const float* bneigh = (const float*)d_in[5];
    const float* gamma  = (const float*)d_in[6];
    const float* beta   = (const float*)d_in[7];
    float* out = (float*)d_out;

    // ws layout: X (20.6MB) | Wc (1MB) | Y (10.3MB) | deg | cnt | col | H8 (5.1MB)
    ushort* X   = (ushort*)d_ws;                          // N_PAD*KDIM bf16
    ushort* Wc  = X + (size_t)N_PAD * KDIM;               // 512*KDIM bf16
    ushort* Y   = Wc + (size_t)DIM * KDIM;                // N_PAD*DIM bf16
    float* deg  = (float*)(Y + (size_t)N_PAD * DIM);      // N f32
    int* cnt    = (int*)(deg + N_NODES);                  // N int
    int* col    = cnt + N_NODES;                          // N*CAP int (2.56MB)
    unsigned char* H8 = (unsigned char*)(col + (size_t)N_NODES * CAP);  // N*DIM fp8

    conv_w<<<(DIM * 128) / 256, 256, 0, stream>>>(Wself, Wneigh, Wc, cnt);
    conv_x<<<(N_PAD * 128) / 256, 256, 0, stream>>>(h, X, H8, eidx, cnt, col);
    gather_agg<<<(N_NODES * 64) / 256, 256, 0, stream>>>(cnt, col, H8, X, deg);

    mfma_gemm<<<NWG, 256, 0, stream>>>(X, Wc, deg, bself, bneigh, Y);

    ln_kernel<<<N_NODES, 256, 0, stream>>>(Y, h, gamma, beta, out);
}

// Round 14
// 71.100 us; speedup vs baseline: 1.1454x; 1.0050x over previous
//
#include <hip/hip_runtime.h>

#define N_NODES 10000
#define N_PAD   10048          // multiple of 64 for BM=64 tiles
#define N_EDGES 160000
#define DIM     512
#define KDIM    1024           // concatenated K = [h | neigh]
#define CAP     64             // per-node edge bucket capacity (max deg ~35)

#define BM 64
#define BN 128
#define BK 64
#define KITERS (KDIM / BK)     // 16
#define NWG    ((N_PAD / BM) * (DIM / BN))   // 628
#define SWZ_Q  (NWG / 8)                     // 78
#define SWZ_R  (NWG % 8)                     // 4

typedef __attribute__((ext_vector_type(8))) short bf16x8;
typedef __attribute__((ext_vector_type(4))) float f32x4;
typedef __attribute__((ext_vector_type(2))) float f32x2;

static __device__ __forceinline__ ushort f2bf(float f) {
    union { float f; unsigned u; } x; x.f = f;
    unsigned u = x.u + 0x7fff + ((x.u >> 16) & 1);   // round-to-nearest-even
    return (ushort)(u >> 16);
}
static __device__ __forceinline__ float b2f(ushort u) {
    union { unsigned u; float f; } x; x.u = ((unsigned)u) << 16; return x.f;
}

// ---------------------------------------------------------------------------
// conv_all = conv_w + conv_x merged (cnt zeroed by a memsetAsync node that
// precedes this kernel in stream order -> bucketing atomics are safe).
//  idx < 65536          : Wc[c][k] = bf16([Wself | Wneigh])
//  idx < N_EDGES        : bucket edge (atomicAdd on cnt)
//  n = idx>>7 < N_PAD   : X left half = bf16(h), H8 = fp8(h), pad rows zeroed
// ---------------------------------------------------------------------------
__global__ __launch_bounds__(256) void conv_all(
    const float* __restrict__ Wself, const float* __restrict__ Wneigh,
    ushort* __restrict__ Wc,
    const float* __restrict__ h, ushort* __restrict__ X,
    unsigned char* __restrict__ H8,
    const int* __restrict__ eidx, int* __restrict__ cnt, int* __restrict__ col)
{
    int idx = blockIdx.x * 256 + threadIdx.x;

    if (idx < DIM * 128) {                   // W conversion (65536 threads)
        int c  = idx >> 7;
        int k8 = idx & 127;
        const float* src = (k8 < 64) ? (Wself + (size_t)c * DIM + k8 * 8)
                                     : (Wneigh + (size_t)c * DIM + (k8 - 64) * 8);
        float4 v0 = *(const float4*)src;
        float4 v1 = *(const float4*)(src + 4);
        ushort* dst = Wc + (size_t)c * KDIM + k8 * 8;
        ushort4 o0 = { f2bf(v0.x), f2bf(v0.y), f2bf(v0.z), f2bf(v0.w) };
        ushort4 o1 = { f2bf(v1.x), f2bf(v1.y), f2bf(v1.z), f2bf(v1.w) };
        *(ushort4*)dst = o0;
        *(ushort4*)(dst + 4) = o1;
    }

    if (idx < N_EDGES) {                     // edge bucketing
        int s = eidx[idx];
        int d = eidx[N_EDGES + idx];
        int p = atomicAdd(&cnt[s], 1);
        if (p < CAP) col[(s << 6) + p] = d;
    }

    int n  = idx >> 7;
    int k8 = idx & 127;
    if (n >= N_PAD) return;
    ushort* dst = X + (size_t)n * KDIM + k8 * 8;
    if (n >= N_NODES) {                      // zero pad row (full 1024)
        ushort4 z = {0, 0, 0, 0};
        *(ushort4*)dst = z;
        *(ushort4*)(dst + 4) = z;
        return;
    }
    if (k8 >= 64) return;                    // right half written by gather
    const float* src = h + (size_t)n * DIM + k8 * 8;
    float4 v0 = *(const float4*)src;
    float4 v1 = *(const float4*)(src + 4);
    ushort4 o0 = { f2bf(v0.x), f2bf(v0.y), f2bf(v0.z), f2bf(v0.w) };
    ushort4 o1 = { f2bf(v1.x), f2bf(v1.y), f2bf(v1.z), f2bf(v1.w) };
    *(ushort4*)dst = o0;
    *(ushort4*)(dst + 4) = o1;
    // fp8 copy for the gather, HW packed converts (2 f32 -> 1 instr)
    uint2 p8;
    int r0 = 0, r1 = 0;
    r0 = __builtin_amdgcn_cvt_pk_fp8_f32(v0.x, v0.y, r0, false);
    r0 = __builtin_amdgcn_cvt_pk_fp8_f32(v0.z, v0.w, r0, true);
    r1 = __builtin_amdgcn_cvt_pk_fp8_f32(v1.x, v1.y, r1, false);
    r1 = __builtin_amdgcn_cvt_pk_fp8_f32(v1.z, v1.w, r1, true);
    p8.x = (unsigned)r0;
    p8.y = (unsigned)r1;
    *(uint2*)(H8 + (size_t)n * DIM + k8 * 8) = p8;
}

// ---------------------------------------------------------------------------
// Gather-aggregate (fp8 source, HW decode): one wave per node; lane owns
// cols lane*8..+7 (8 B/edge).  Bucketed edges broadcast via shfl; unroll x8.
// ---------------------------------------------------------------------------
__global__ __launch_bounds__(256) void gather_agg(
    const int* __restrict__ cnt, const int* __restrict__ col,
    const unsigned char* __restrict__ H8,
    ushort* __restrict__ X, float* __restrict__ deg)
{
    int gid  = blockIdx.x * 256 + threadIdx.x;
    int n    = gid >> 6;
    int lane = gid & 63;
    if (n >= N_NODES) return;
    int d  = cnt[n];
    int nk = d < CAP ? d : CAP;

    int myc = (lane < nk) ? col[(n << 6) + lane] : 0;

    f32x2 a01 = {0.f, 0.f}, a23 = {0.f, 0.f}, a45 = {0.f, 0.f}, a67 = {0.f, 0.f};
    int k = 0;
    for (; k + 8 <= nk; k += 8) {
        uint2 v[8];
#pragma unroll
        for (int u = 0; u < 8; ++u) {
            int dst = __shfl(myc, k + u);
            v[u] = *(const uint2*)(H8 + (size_t)dst * DIM + lane * 8);
        }
#pragma unroll
        for (int u = 0; u < 8; ++u) {
            a01 += __builtin_amdgcn_cvt_pk_f32_fp8((int)v[u].x, false);
            a23 += __builtin_amdgcn_cvt_pk_f32_fp8((int)v[u].x, true);
            a45 += __builtin_amdgcn_cvt_pk_f32_fp8((int)v[u].y, false);
            a67 += __builtin_amdgcn_cvt_pk_f32_fp8((int)v[u].y, true);
        }
    }
    for (; k < nk; ++k) {
        int dst = __shfl(myc, k);
        uint2 v = *(const uint2*)(H8 + (size_t)dst * DIM + lane * 8);
        a01 += __builtin_amdgcn_cvt_pk_f32_fp8((int)v.x, false);
        a23 += __builtin_amdgcn_cvt_pk_f32_fp8((int)v.x, true);
        a45 += __builtin_amdgcn_cvt_pk_f32_fp8((int)v.y, false);
        a67 += __builtin_amdgcn_cvt_pk_f32_fp8((int)v.y, true);
    }
    float inv = 1.0f / fmaxf((float)d, 1.0f);
    ushort* xr = X + (size_t)n * KDIM + DIM + lane * 8;
    ushort4 o0 = { f2bf(a01[0] * inv), f2bf(a01[1] * inv),
                   f2bf(a23[0] * inv), f2bf(a23[1] * inv) };
    ushort4 o1 = { f2bf(a45[0] * inv), f2bf(a45[1] * inv),
                   f2bf(a67[0] * inv), f2bf(a67[1] * inv) };
    *(ushort4*)xr       = o0;
    *(ushort4*)(xr + 4) = o1;
    if (lane == 0) deg[n] = (float)d;
}

// ---------------------------------------------------------------------------
// MFMA GEMM (R13-best): 256 thr / 4 waves (2x2), tile 64x128, wave 32x64.
// global_load_lds(16B) staging, XOR-swizzled source, dbuf, 1 barrier/K-step,
// bijective XCD swizzle on the 1-D grid (m204).
// ---------------------------------------------------------------------------
#define MFMA(A, B, C) __builtin_amdgcn_mfma_f32_16x16x32_bf16(A, B, C, 0, 0, 0)

__global__ __launch_bounds__(256) void mfma_gemm(
    const ushort* __restrict__ X, const ushort* __restrict__ Wc,
    const float* __restrict__ deg,
    const float* __restrict__ bself, const float* __restrict__ bneigh,
    ushort* __restrict__ Y)
{
    __shared__ ushort As[2][BM * BK];    // 2 x  8 KB, linear (DMA dest)
    __shared__ ushort Bs[2][BN * BK];    // 2 x 16 KB

    // bijective XCD swizzle (NWG=628, Q=78, R=4)
    const int orig = blockIdx.x;
    const int xcd  = orig & 7;
    const int loc  = orig >> 3;
    const int wgid = (xcd < SWZ_R ? xcd * (SWZ_Q + 1)
                                  : SWZ_R * (SWZ_Q + 1) + (xcd - SWZ_R) * SWZ_Q) + loc;
    const int row0 = (wgid >> 2) * BM;   // 157 row-groups
    const int col0 = (wgid & 3) * BN;    // 4 col-blocks

    const int t    = threadIdx.x;
    const int lane = t & 63;
    const int wave = t >> 6;
    const int wr   = (wave >> 1) * 32;   // wave row offset in tile
    const int wc   = (wave & 1) * 64;    // wave col offset in tile
    const int fr   = lane & 15;
    const int fq   = lane >> 4;          // 0..3

#define STAGE(BUF, IT)                                                         \
    {                                                                          \
        const int k0s = (IT) * BK;                                             \
        _Pragma("unroll")                                                      \
        for (int s = 0; s < 2; ++s) {                                          \
            int c = t + s * 256;                                               \
            int row = c >> 3;                                                  \
            int ks = k0s + (((c & 7) ^ (row & 7)) << 3);                       \
            __builtin_amdgcn_global_load_lds(                                  \
                (const __attribute__((address_space(1))) void*)                \
                    (X + (size_t)(row0 + row) * KDIM + ks),                    \
                (__attribute__((address_space(3))) void*)(&As[BUF][c * 8]),    \
                16, 0, 0);                                                     \
        }                                                                      \
        _Pragma("unroll")                                                      \
        for (int s = 0; s < 4; ++s) {                                          \
            int c = t + s * 256;                                               \
            int row = c >> 3;                                                  \
            int ks = k0s + (((c & 7) ^ (row & 7)) << 3);                       \
            __builtin_amdgcn_global_load_lds(                                  \
                (const __attribute__((address_space(1))) void*)                \
                    (Wc + (size_t)(col0 + row) * KDIM + ks),                   \
                (__attribute__((address_space(3))) void*)(&Bs[BUF][c * 8]),    \
                16, 0, 0);                                                     \
        }                                                                      \
    }

    f32x4 acc[2][4];
#pragma unroll
    for (int i = 0; i < 2; ++i)
#pragma unroll
        for (int j = 0; j < 4; ++j) acc[i][j] = (f32x4){0.f, 0.f, 0.f, 0.f};

    STAGE(0, 0);
    __syncthreads();                     // drains vmcnt(0) + barrier

    int buf = 0;
    for (int it = 0; it < KITERS; ++it) {
        if (it + 1 < KITERS) STAGE(buf ^ 1, it + 1);   // async, overlaps MFMAs

        const ushort* as = As[buf];
        const ushort* bs = Bs[buf];
#pragma unroll
        for (int inner = 0; inner < 2; ++inner) {
            const int sw = (((inner * 4 + fq) ^ (fr & 7)) << 3);  // swizzled k-off
            bf16x8 a0 = *(const bf16x8*)(as + (wr + fr) * BK + sw);
            bf16x8 a1 = *(const bf16x8*)(as + (wr + 16 + fr) * BK + sw);
#pragma unroll
            for (int j = 0; j < 4; ++j) {
                bf16x8 bv = *(const bf16x8*)(bs + (wc + j * 16 + fr) * BK + sw);
                acc[0][j] = MFMA(a0, bv, acc[0][j]);
                acc[1][j] = MFMA(a1, bv, acc[1][j]);
            }
        }
        __syncthreads();                 // next-tile DMA drained; reads done
        buf ^= 1;
    }

    // epilogue: Y = bf16( relu(acc + bself + (deg>0)*bneigh) )
#pragma unroll
    for (int i = 0; i < 2; ++i) {
#pragma unroll
        for (int r = 0; r < 4; ++r) {
            int gr = row0 + wr + i * 16 + fq * 4 + r;
            float hb = (gr < N_NODES && deg[gr] > 0.0f) ? 1.0f : 0.0f;
            ushort* yrow = Y + (size_t)gr * DIM;
#pragma unroll
            for (int j = 0; j < 4; ++j) {
                int gc = col0 + wc + j * 16 + fr;
                float v = fmaxf(acc[i][j][r] + bself[gc] + hb * bneigh[gc], 0.f);
                yrow[gc] = f2bf(v);
            }
        }
    }
}

// ---------------------------------------------------------------------------
// LayerNorm: out = LN(h + Y), one 256-thread block per node row.
// ---------------------------------------------------------------------------
__global__ __launch_bounds__(256) void ln_kernel(
    const ushort* __restrict__ Y, const float* __restrict__ h,
    const float* __restrict__ g, const float* __restrict__ b,
    float* __restrict__ out)
{
    __shared__ float red[8];
    int n = blockIdx.x;
    int t = threadIdx.x;
    float2 hv = *(const float2*)(h + (size_t)n * DIM + t * 2);
    ushort2 yv = *(const ushort2*)(Y + (size_t)n * DIM + t * 2);
    float v0 = hv.x + b2f(yv.x);
    float v1 = hv.y + b2f(yv.y);
    float s  = v0 + v1;
    float sq = v0 * v0 + v1 * v1;
#pragma unroll
    for (int off = 32; off >= 1; off >>= 1) {
        s  += __shfl_xor(s, off);
        sq += __shfl_xor(sq, off);
    }
    int wave = t >> 6;
    if ((t & 63) == 0) { red[wave] = s; red[4 + wave] = sq; }
    __syncthreads();
    s  = red[0] + red[1] + red[2] + red[3];
    sq = red[4] + red[5] + red[6] + red[7];
    float mean = s * (1.0f / DIM);
    float var  = sq * (1.0f / DIM) - mean * mean;
    float rstd = rsqrtf(var + 1e-5f);
    float2 gv = *(const float2*)(g + t * 2);
    float2 bv = *(const float2*)(b + t * 2);
    float2 o;
    o.x = (v0 - mean) * rstd * gv.x + bv.x;
    o.y = (v1 - mean) * rstd * gv.y + bv.y;
    *(float2*)(out + (size_t)n * DIM + t * 2) = o;
}

// ---------------------------------------------------------------------------
extern "C" void kernel_launch(void* const* d_in, const int* in_sizes, int n_in,
                              void* d_out, int out_size, void* d_ws, size_t ws_size,
                              hipStream_t stream)
{
    const float* h      = (const float*)d_in[0];
    const int*   eidx   = (const int*)d_in[1];
    const float* Wself  = (const float*)d_in[2];
    const float* bself  = (const float*)d_in[3];
    const float* Wneigh = (const float*)d_in[4];
    const float* bneigh = (const float*)d_in[5];
    const float* gamma  = (const float*)d_in[6];
    const float* beta   = (const float*)d_in[7];
    float* out = (float*)d_out;

    // ws layout: X (20.6MB) | Wc (1MB) | Y (10.3MB) | deg | cnt | col | H8 (5.1MB)
    ushort* X   = (ushort*)d_ws;                          // N_PAD*KDIM bf16
    ushort* Wc  = X + (size_t)N_PAD * KDIM;               // 512*KDIM bf16
    ushort* Y   = Wc + (size_t)DIM * KDIM;                // N_PAD*DIM bf16
    float* deg  = (float*)(Y + (size_t)N_PAD * DIM);      // N f32
    int* cnt    = (int*)(deg + N_NODES);                  // N int
    int* col    = cnt + N_NODES;                          // N*CAP int (2.56MB)
    unsigned char* H8 = (unsigned char*)(col + (size_t)N_NODES * CAP);  // N*DIM fp8

    // cnt zero as a memset NODE (~1 us) instead of a kernel boundary (~5-7 us)
    hipMemsetAsync(cnt, 0, N_NODES * sizeof(int), stream);

    conv_all<<<(N_PAD * 128) / 256, 256, 0, stream>>>(
        Wself, Wneigh, Wc, h, X, H8, eidx, cnt, col);

    gather_agg<<<(N_NODES * 64) / 256, 256, 0, stream>>>(cnt, col, H8, X, deg);

    mfma_gemm<<<NWG, 256, 0, stream>>>(X, Wc, deg, bself, bneigh, Y);

    ln_kernel<<<N_NODES, 256, 0, stream>>>(Y, h, gamma, beta, out);
}

// Round 15
// 71.043 us; speedup vs baseline: 1.1463x; 1.0008x over previous
//
#include <hip/hip_runtime.h>

#define N_NODES 10000
#define N_PAD   10048          // multiple of 64 for BM=64 tiles
#define N_EDGES 160000
#define DIM     512
#define KDIM    1024           // concatenated K = [h | neigh]
#define CAP     64             // per-node edge bucket capacity (max deg ~35)

#define BM 64
#define BN 128
#define BK 64
#define KITERS (KDIM / BK)     // 16
#define NWG    ((N_PAD / BM) * (DIM / BN))   // 628
#define SWZ_Q  (NWG / 8)                     // 78
#define SWZ_R  (NWG % 8)                     // 4

typedef __attribute__((ext_vector_type(8))) short bf16x8;
typedef __attribute__((ext_vector_type(4))) float f32x4;
typedef __attribute__((ext_vector_type(2))) float f32x2;

static __device__ __forceinline__ ushort f2bf(float f) {
    union { float f; unsigned u; } x; x.f = f;
    unsigned u = x.u + 0x7fff + ((x.u >> 16) & 1);   // round-to-nearest-even
    return (ushort)(u >> 16);
}
static __device__ __forceinline__ float b2f(ushort u) {
    union { unsigned u; float f; } x; x.u = ((unsigned)u) << 16; return x.f;
}

// ---------------------------------------------------------------------------
// conv_all: W convert + X-left/H8 convert + edge bucketing (cnt pre-zeroed
// by the memset node).
// ---------------------------------------------------------------------------
__global__ __launch_bounds__(256) void conv_all(
    const float* __restrict__ Wself, const float* __restrict__ Wneigh,
    ushort* __restrict__ Wc,
    const float* __restrict__ h, ushort* __restrict__ X,
    unsigned char* __restrict__ H8,
    const int* __restrict__ eidx, int* __restrict__ cnt, int* __restrict__ col)
{
    int idx = blockIdx.x * 256 + threadIdx.x;

    if (idx < DIM * 128) {                   // W conversion (65536 threads)
        int c  = idx >> 7;
        int k8 = idx & 127;
        const float* src = (k8 < 64) ? (Wself + (size_t)c * DIM + k8 * 8)
                                     : (Wneigh + (size_t)c * DIM + (k8 - 64) * 8);
        float4 v0 = *(const float4*)src;
        float4 v1 = *(const float4*)(src + 4);
        ushort* dst = Wc + (size_t)c * KDIM + k8 * 8;
        ushort4 o0 = { f2bf(v0.x), f2bf(v0.y), f2bf(v0.z), f2bf(v0.w) };
        ushort4 o1 = { f2bf(v1.x), f2bf(v1.y), f2bf(v1.z), f2bf(v1.w) };
        *(ushort4*)dst = o0;
        *(ushort4*)(dst + 4) = o1;
    }

    if (idx < N_EDGES) {                     // edge bucketing
        int s = eidx[idx];
        int d = eidx[N_EDGES + idx];
        int p = atomicAdd(&cnt[s], 1);
        if (p < CAP) col[(s << 6) + p] = d;
    }

    int n  = idx >> 7;
    int k8 = idx & 127;
    if (n >= N_PAD) return;
    ushort* dst = X + (size_t)n * KDIM + k8 * 8;
    if (n >= N_NODES) {                      // zero pad row (full 1024)
        ushort4 z = {0, 0, 0, 0};
        *(ushort4*)dst = z;
        *(ushort4*)(dst + 4) = z;
        return;
    }
    if (k8 >= 64) return;                    // right half written by gather
    const float* src = h + (size_t)n * DIM + k8 * 8;
    float4 v0 = *(const float4*)src;
    float4 v1 = *(const float4*)(src + 4);
    ushort4 o0 = { f2bf(v0.x), f2bf(v0.y), f2bf(v0.z), f2bf(v0.w) };
    ushort4 o1 = { f2bf(v1.x), f2bf(v1.y), f2bf(v1.z), f2bf(v1.w) };
    *(ushort4*)dst = o0;
    *(ushort4*)(dst + 4) = o1;
    // fp8 copy for the gather, HW packed converts (2 f32 -> 1 instr)
    uint2 p8;
    int r0 = 0, r1 = 0;
    r0 = __builtin_amdgcn_cvt_pk_fp8_f32(v0.x, v0.y, r0, false);
    r0 = __builtin_amdgcn_cvt_pk_fp8_f32(v0.z, v0.w, r0, true);
    r1 = __builtin_amdgcn_cvt_pk_fp8_f32(v1.x, v1.y, r1, false);
    r1 = __builtin_amdgcn_cvt_pk_fp8_f32(v1.z, v1.w, r1, true);
    p8.x = (unsigned)r0;
    p8.y = (unsigned)r1;
    *(uint2*)(H8 + (size_t)n * DIM + k8 * 8) = p8;
}

// ---------------------------------------------------------------------------
// Gather-aggregate (fp8 source, HW decode): one wave per node; lane owns
// cols lane*8..+7 (8 B/edge).  Bucketed edges broadcast via shfl; unroll x8.
// ---------------------------------------------------------------------------
__global__ __launch_bounds__(256) void gather_agg(
    const int* __restrict__ cnt, const int* __restrict__ col,
    const unsigned char* __restrict__ H8,
    ushort* __restrict__ X, float* __restrict__ deg)
{
    int gid  = blockIdx.x * 256 + threadIdx.x;
    int n    = gid >> 6;
    int lane = gid & 63;
    if (n >= N_NODES) return;
    int d  = cnt[n];
    int nk = d < CAP ? d : CAP;

    int myc = (lane < nk) ? col[(n << 6) + lane] : 0;

    f32x2 a01 = {0.f, 0.f}, a23 = {0.f, 0.f}, a45 = {0.f, 0.f}, a67 = {0.f, 0.f};
    int k = 0;
    for (; k + 8 <= nk; k += 8) {
        uint2 v[8];
#pragma unroll
        for (int u = 0; u < 8; ++u) {
            int dst = __shfl(myc, k + u);
            v[u] = *(const uint2*)(H8 + (size_t)dst * DIM + lane * 8);
        }
#pragma unroll
        for (int u = 0; u < 8; ++u) {
            a01 += __builtin_amdgcn_cvt_pk_f32_fp8((int)v[u].x, false);
            a23 += __builtin_amdgcn_cvt_pk_f32_fp8((int)v[u].x, true);
            a45 += __builtin_amdgcn_cvt_pk_f32_fp8((int)v[u].y, false);
            a67 += __builtin_amdgcn_cvt_pk_f32_fp8((int)v[u].y, true);
        }
    }
    for (; k < nk; ++k) {
        int dst = __shfl(myc, k);
        uint2 v = *(const uint2*)(H8 + (size_t)dst * DIM + lane * 8);
        a01 += __builtin_amdgcn_cvt_pk_f32_fp8((int)v.x, false);
        a23 += __builtin_amdgcn_cvt_pk_f32_fp8((int)v.x, true);
        a45 += __builtin_amdgcn_cvt_pk_f32_fp8((int)v.y, false);
        a67 += __builtin_amdgcn_cvt_pk_f32_fp8((int)v.y, true);
    }
    float inv = 1.0f / fmaxf((float)d, 1.0f);
    ushort* xr = X + (size_t)n * KDIM + DIM + lane * 8;
    ushort4 o0 = { f2bf(a01[0] * inv), f2bf(a01[1] * inv),
                   f2bf(a23[0] * inv), f2bf(a23[1] * inv) };
    ushort4 o1 = { f2bf(a45[0] * inv), f2bf(a45[1] * inv),
                   f2bf(a67[0] * inv), f2bf(a67[1] * inv) };
    *(ushort4*)xr       = o0;
    *(ushort4*)(xr + 4) = o1;
    if (lane == 0) deg[n] = (float)d;
}

// ---------------------------------------------------------------------------
// MFMA GEMM (R13-best, unchanged): 256 thr / 4 waves (2x2), tile 64x128,
// wave 32x64.  global_load_lds(16B) staging, XOR-swizzled source, dbuf,
// 1 barrier/K-step, bijective XCD swizzle (m204).
// ---------------------------------------------------------------------------
#define MFMA(A, B, C) __builtin_amdgcn_mfma_f32_16x16x32_bf16(A, B, C, 0, 0, 0)

__global__ __launch_bounds__(256) void mfma_gemm(
    const ushort* __restrict__ X, const ushort* __restrict__ Wc,
    const float* __restrict__ deg,
    const float* __restrict__ bself, const float* __restrict__ bneigh,
    ushort* __restrict__ Y)
{
    __shared__ ushort As[2][BM * BK];    // 2 x  8 KB, linear (DMA dest)
    __shared__ ushort Bs[2][BN * BK];    // 2 x 16 KB

    // bijective XCD swizzle (NWG=628, Q=78, R=4)
    const int orig = blockIdx.x;
    const int xcd  = orig & 7;
    const int loc  = orig >> 3;
    const int wgid = (xcd < SWZ_R ? xcd * (SWZ_Q + 1)
                                  : SWZ_R * (SWZ_Q + 1) + (xcd - SWZ_R) * SWZ_Q) + loc;
    const int row0 = (wgid >> 2) * BM;   // 157 row-groups
    const int col0 = (wgid & 3) * BN;    // 4 col-blocks

    const int t    = threadIdx.x;
    const int lane = t & 63;
    const int wave = t >> 6;
    const int wr   = (wave >> 1) * 32;   // wave row offset in tile
    const int wc   = (wave & 1) * 64;    // wave col offset in tile
    const int fr   = lane & 15;
    const int fq   = lane >> 4;          // 0..3

#define STAGE(BUF, IT)                                                         \
    {                                                                          \
        const int k0s = (IT) * BK;                                             \
        _Pragma("unroll")                                                      \
        for (int s = 0; s < 2; ++s) {                                          \
            int c = t + s * 256;                                               \
            int row = c >> 3;                                                  \
            int ks = k0s + (((c & 7) ^ (row & 7)) << 3);                       \
            __builtin_amdgcn_global_load_lds(                                  \
                (const __attribute__((address_space(1))) void*)                \
                    (X + (size_t)(row0 + row) * KDIM + ks),                    \
                (__attribute__((address_space(3))) void*)(&As[BUF][c * 8]),    \
                16, 0, 0);                                                     \
        }                                                                      \
        _Pragma("unroll")                                                      \
        for (int s = 0; s < 4; ++s) {                                          \
            int c = t + s * 256;                                               \
            int row = c >> 3;                                                  \
            int ks = k0s + (((c & 7) ^ (row & 7)) << 3);                       \
            __builtin_amdgcn_global_load_lds(                                  \
                (const __attribute__((address_space(1))) void*)                \
                    (Wc + (size_t)(col0 + row) * KDIM + ks),                   \
                (__attribute__((address_space(3))) void*)(&Bs[BUF][c * 8]),    \
                16, 0, 0);                                                     \
        }                                                                      \
    }

    f32x4 acc[2][4];
#pragma unroll
    for (int i = 0; i < 2; ++i)
#pragma unroll
        for (int j = 0; j < 4; ++j) acc[i][j] = (f32x4){0.f, 0.f, 0.f, 0.f};

    STAGE(0, 0);
    __syncthreads();                     // drains vmcnt(0) + barrier

    int buf = 0;
    for (int it = 0; it < KITERS; ++it) {
        if (it + 1 < KITERS) STAGE(buf ^ 1, it + 1);   // async, overlaps MFMAs

        const ushort* as = As[buf];
        const ushort* bs = Bs[buf];
#pragma unroll
        for (int inner = 0; inner < 2; ++inner) {
            const int sw = (((inner * 4 + fq) ^ (fr & 7)) << 3);  // swizzled k-off
            bf16x8 a0 = *(const bf16x8*)(as + (wr + fr) * BK + sw);
            bf16x8 a1 = *(const bf16x8*)(as + (wr + 16 + fr) * BK + sw);
#pragma unroll
            for (int j = 0; j < 4; ++j) {
                bf16x8 bv = *(const bf16x8*)(bs + (wc + j * 16 + fr) * BK + sw);
                acc[0][j] = MFMA(a0, bv, acc[0][j]);
                acc[1][j] = MFMA(a1, bv, acc[1][j]);
            }
        }
        __syncthreads();                 // next-tile DMA drained; reads done
        buf ^= 1;
    }

    // epilogue: Y = bf16( relu(acc + bself + (deg>0)*bneigh) )
#pragma unroll
    for (int i = 0; i < 2; ++i) {
#pragma unroll
        for (int r = 0; r < 4; ++r) {
            int gr = row0 + wr + i * 16 + fq * 4 + r;
            float hb = (gr < N_NODES && deg[gr] > 0.0f) ? 1.0f : 0.0f;
            ushort* yrow = Y + (size_t)gr * DIM;
#pragma unroll
            for (int j = 0; j < 4; ++j) {
                int gc = col0 + wc + j * 16 + fr;
                float v = fmaxf(acc[i][j][r] + bself[gc] + hb * bneigh[gc], 0.f);
                yrow[gc] = f2bf(v);
            }
        }
    }
}

// ---------------------------------------------------------------------------
// LayerNorm: out = LN(bf16(h) + Y).  Residual read from X left half (bf16,
// 10 MB) instead of f32 h (20 MB).  2 rows per 512-thread block (5000 blocks
// cover 10000 rows exactly -> uniform control flow around barriers).
// ---------------------------------------------------------------------------
__global__ __launch_bounds__(512) void ln_kernel(
    const ushort* __restrict__ Y, const ushort* __restrict__ Xl,
    const float* __restrict__ g, const float* __restrict__ b,
    float* __restrict__ out)
{
    __shared__ float red[2][8];
    const int half = threadIdx.x >> 8;        // row within block: 0..1
    const int t    = threadIdx.x & 255;       // 0..255, 2 cols each
    const int n    = blockIdx.x * 2 + half;   // 5000*2 = 10000 exact

    ushort2 yv = *(const ushort2*)(Y  + (size_t)n * DIM  + t * 2);
    ushort2 xv = *(const ushort2*)(Xl + (size_t)n * KDIM + t * 2);
    float v0 = b2f(xv.x) + b2f(yv.x);
    float v1 = b2f(xv.y) + b2f(yv.y);
    float s  = v0 + v1;
    float sq = v0 * v0 + v1 * v1;
#pragma unroll
    for (int off = 32; off >= 1; off >>= 1) {
        s  += __shfl_xor(s, off);
        sq += __shfl_xor(sq, off);
    }
    int wave = t >> 6;                        // wave within this row: 0..3
    if ((t & 63) == 0) { red[half][wave] = s; red[half][4 + wave] = sq; }
    __syncthreads();
    s  = red[half][0] + red[half][1] + red[half][2] + red[half][3];
    sq = red[half][4] + red[half][5] + red[half][6] + red[half][7];
    float mean = s * (1.0f / DIM);
    float var  = sq * (1.0f / DIM) - mean * mean;
    float rstd = rsqrtf(var + 1e-5f);
    float2 gv = *(const float2*)(g + t * 2);
    float2 bv = *(const float2*)(b + t * 2);
    float2 o;
    o.x = (v0 - mean) * rstd * gv.x + bv.x;
    o.y = (v1 - mean) * rstd * gv.y + bv.y;
    *(float2*)(out + (size_t)n * DIM + t * 2) = o;
}

// ---------------------------------------------------------------------------
extern "C" void kernel_launch(void* const* d_in, const int* in_sizes, int n_in,
                              void* d_out, int out_size, void* d_ws, size_t ws_size,
                              hipStream_t stream)
{
    const float* h      = (const float*)d_in[0];
    const int*   eidx   = (const int*)d_in[1];
    const float* Wself  = (const float*)d_in[2];
    const float* bself  = (const float*)d_in[3];
    const float* Wneigh = (const float*)d_in[4];
    const float* bneigh = (const float*)d_in[5];
    const float* gamma  = (const float*)d_in[6];
    const float* beta   = (const float*)d_in[7];
    float* out = (float*)d_out;

    // ws layout: X (20.6MB) | Wc (1MB) | Y (10.3MB) | deg | cnt | col | H8 (5.1MB)
    ushort* X   = (ushort*)d_ws;                          // N_PAD*KDIM bf16
    ushort* Wc  = X + (size_t)N_PAD * KDIM;               // 512*KDIM bf16
    ushort* Y   = Wc + (size_t)DIM * KDIM;                // N_PAD*DIM bf16
    float* deg  = (float*)(Y + (size_t)N_PAD * DIM);      // N f32
    int* cnt    = (int*)(deg + N_NODES);                  // N int
    int* col    = cnt + N_NODES;                          // N*CAP int (2.56MB)
    unsigned char* H8 = (unsigned char*)(col + (size_t)N_NODES * CAP);  // N*DIM fp8

    hipMemsetAsync(cnt, 0, N_NODES * sizeof(int), stream);

    conv_all<<<(N_PAD * 128) / 256, 256, 0, stream>>>(
        Wself, Wneigh, Wc, h, X, H8, eidx, cnt, col);

    gather_agg<<<(N_NODES * 64) / 256, 256, 0, stream>>>(cnt, col, H8, X, deg);

    mfma_gemm<<<NWG, 256, 0, stream>>>(X, Wc, deg, bself, bneigh, Y);

    ln_kernel<<<N_NODES / 2, 512, 0, stream>>>(Y, X, gamma, beta, out);
}

// Round 16
// 68.778 us; speedup vs baseline: 1.1841x; 1.0329x over previous
//
#include <hip/hip_runtime.h>

#define N_NODES 10000
#define N_PAD   10048          // multiple of 64 for BM=64 tiles
#define N_EDGES 160000
#define DIM     512
#define KDIM    1024           // concatenated K = [h | neigh]
#define CAP     64             // per-node edge bucket capacity (max deg ~35)

#define BM 64
#define BN 128
#define BK 32
#define KITERS (DIM / BK)      // 16 per K-half
#define NWG    ((N_PAD / BM) * (DIM / BN) * 2)   // 157*4*2 = 1256
#define SWZ_Q  (NWG / 8)                         // 157
#define SWZ_R  (NWG % 8)                         // 0

typedef __attribute__((ext_vector_type(8))) short bf16x8;
typedef __attribute__((ext_vector_type(4))) float f32x4;
typedef __attribute__((ext_vector_type(2))) float f32x2;

static __device__ __forceinline__ ushort f2bf(float f) {
    union { float f; unsigned u; } x; x.f = f;
    unsigned u = x.u + 0x7fff + ((x.u >> 16) & 1);   // round-to-nearest-even
    return (ushort)(u >> 16);
}
static __device__ __forceinline__ float b2f(ushort u) {
    union { unsigned u; float f; } x; x.u = ((unsigned)u) << 16; return x.f;
}

// ---------------------------------------------------------------------------
// conv_all: W convert + X-left/H8 convert + edge bucketing (cnt pre-zeroed
// by the memset node).
// ---------------------------------------------------------------------------
__global__ __launch_bounds__(256) void conv_all(
    const float* __restrict__ Wself, const float* __restrict__ Wneigh,
    ushort* __restrict__ Wc,
    const float* __restrict__ h, ushort* __restrict__ X,
    unsigned char* __restrict__ H8,
    const int* __restrict__ eidx, int* __restrict__ cnt, int* __restrict__ col)
{
    int idx = blockIdx.x * 256 + threadIdx.x;

    if (idx < DIM * 128) {                   // W conversion (65536 threads)
        int c  = idx >> 7;
        int k8 = idx & 127;
        const float* src = (k8 < 64) ? (Wself + (size_t)c * DIM + k8 * 8)
                                     : (Wneigh + (size_t)c * DIM + (k8 - 64) * 8);
        float4 v0 = *(const float4*)src;
        float4 v1 = *(const float4*)(src + 4);
        ushort* dst = Wc + (size_t)c * KDIM + k8 * 8;
        ushort4 o0 = { f2bf(v0.x), f2bf(v0.y), f2bf(v0.z), f2bf(v0.w) };
        ushort4 o1 = { f2bf(v1.x), f2bf(v1.y), f2bf(v1.z), f2bf(v1.w) };
        *(ushort4*)dst = o0;
        *(ushort4*)(dst + 4) = o1;
    }

    if (idx < N_EDGES) {                     // edge bucketing
        int s = eidx[idx];
        int d = eidx[N_EDGES + idx];
        int p = atomicAdd(&cnt[s], 1);
        if (p < CAP) col[(s << 6) + p] = d;
    }

    int n  = idx >> 7;
    int k8 = idx & 127;
    if (n >= N_PAD) return;
    ushort* dst = X + (size_t)n * KDIM + k8 * 8;
    if (n >= N_NODES) {                      // zero pad row (full 1024)
        ushort4 z = {0, 0, 0, 0};
        *(ushort4*)dst = z;
        *(ushort4*)(dst + 4) = z;
        return;
    }
    if (k8 >= 64) return;                    // right half written by gather
    const float* src = h + (size_t)n * DIM + k8 * 8;
    float4 v0 = *(const float4*)src;
    float4 v1 = *(const float4*)(src + 4);
    ushort4 o0 = { f2bf(v0.x), f2bf(v0.y), f2bf(v0.z), f2bf(v0.w) };
    ushort4 o1 = { f2bf(v1.x), f2bf(v1.y), f2bf(v1.z), f2bf(v1.w) };
    *(ushort4*)dst = o0;
    *(ushort4*)(dst + 4) = o1;
    // fp8 copy for the gather, HW packed converts (2 f32 -> 1 instr)
    uint2 p8;
    int r0 = 0, r1 = 0;
    r0 = __builtin_amdgcn_cvt_pk_fp8_f32(v0.x, v0.y, r0, false);
    r0 = __builtin_amdgcn_cvt_pk_fp8_f32(v0.z, v0.w, r0, true);
    r1 = __builtin_amdgcn_cvt_pk_fp8_f32(v1.x, v1.y, r1, false);
    r1 = __builtin_amdgcn_cvt_pk_fp8_f32(v1.z, v1.w, r1, true);
    p8.x = (unsigned)r0;
    p8.y = (unsigned)r1;
    *(uint2*)(H8 + (size_t)n * DIM + k8 * 8) = p8;
}

// ---------------------------------------------------------------------------
// Gather-aggregate (fp8 source, HW decode): one wave per node; lane owns
// cols lane*8..+7 (8 B/edge).  Bucketed edges broadcast via shfl; unroll x8.
// ---------------------------------------------------------------------------
__global__ __launch_bounds__(256) void gather_agg(
    const int* __restrict__ cnt, const int* __restrict__ col,
    const unsigned char* __restrict__ H8,
    ushort* __restrict__ X, float* __restrict__ deg)
{
    int gid  = blockIdx.x * 256 + threadIdx.x;
    int n    = gid >> 6;
    int lane = gid & 63;
    if (n >= N_NODES) return;
    int d  = cnt[n];
    int nk = d < CAP ? d : CAP;

    int myc = (lane < nk) ? col[(n << 6) + lane] : 0;

    f32x2 a01 = {0.f, 0.f}, a23 = {0.f, 0.f}, a45 = {0.f, 0.f}, a67 = {0.f, 0.f};
    int k = 0;
    for (; k + 8 <= nk; k += 8) {
        uint2 v[8];
#pragma unroll
        for (int u = 0; u < 8; ++u) {
            int dst = __shfl(myc, k + u);
            v[u] = *(const uint2*)(H8 + (size_t)dst * DIM + lane * 8);
        }
#pragma unroll
        for (int u = 0; u < 8; ++u) {
            a01 += __builtin_amdgcn_cvt_pk_f32_fp8((int)v[u].x, false);
            a23 += __builtin_amdgcn_cvt_pk_f32_fp8((int)v[u].x, true);
            a45 += __builtin_amdgcn_cvt_pk_f32_fp8((int)v[u].y, false);
            a67 += __builtin_amdgcn_cvt_pk_f32_fp8((int)v[u].y, true);
        }
    }
    for (; k < nk; ++k) {
        int dst = __shfl(myc, k);
        uint2 v = *(const uint2*)(H8 + (size_t)dst * DIM + lane * 8);
        a01 += __builtin_amdgcn_cvt_pk_f32_fp8((int)v.x, false);
        a23 += __builtin_amdgcn_cvt_pk_f32_fp8((int)v.x, true);
        a45 += __builtin_amdgcn_cvt_pk_f32_fp8((int)v.y, false);
        a67 += __builtin_amdgcn_cvt_pk_f32_fp8((int)v.y, true);
    }
    float inv = 1.0f / fmaxf((float)d, 1.0f);
    ushort* xr = X + (size_t)n * KDIM + DIM + lane * 8;
    ushort4 o0 = { f2bf(a01[0] * inv), f2bf(a01[1] * inv),
                   f2bf(a23[0] * inv), f2bf(a23[1] * inv) };
    ushort4 o1 = { f2bf(a45[0] * inv), f2bf(a45[1] * inv),
                   f2bf(a67[0] * inv), f2bf(a67[1] * inv) };
    *(ushort4*)xr       = o0;
    *(ushort4*)(xr + 4) = o1;
    if (lane == 0) deg[n] = (float)d;
}

// ---------------------------------------------------------------------------
// MFMA GEMM, split-K x2: block (row-group, col-block, kb) computes the
// K-half kb of a 64x128 tile; partial written raw-bf16 to Y[kb].
// BK=32 -> LDS 24 KB -> 6 blocks/CU; grid 1256 = 4.9 blocks/CU (~20 waves/CU,
// 2x the latency-hiding pool of R15's 628-grid).  Staged bytes unchanged.
// global_load_lds(16B), XOR-swizzled source (mod-4 chunks), dbuf,
// 1 barrier/K-step, bijective XCD swizzle.
// ---------------------------------------------------------------------------
#define MFMA(A, B, C) __builtin_amdgcn_mfma_f32_16x16x32_bf16(A, B, C, 0, 0, 0)

__global__ __launch_bounds__(256) void mfma_gemm(
    const ushort* __restrict__ X, const ushort* __restrict__ Wc,
    ushort* __restrict__ Y)
{
    __shared__ ushort As[2][BM * BK];    // 2 x 4 KB, linear (DMA dest)
    __shared__ ushort Bs[2][BN * BK];    // 2 x 8 KB

    // bijective XCD swizzle (NWG=1256, Q=157, R=0): wgid = xcd*157 + loc
    const int orig = blockIdx.x;
    const int wgid = (orig & 7) * SWZ_Q + (orig >> 3);
    const int kb   = wgid & 1;                 // K-half: 0=self, 1=neigh
    const int col0 = ((wgid >> 1) & 3) * BN;
    const int row0 = (wgid >> 3) * BM;         // [0,157)

    const int t    = threadIdx.x;
    const int lane = t & 63;
    const int wave = t >> 6;
    const int wr   = (wave >> 1) * 32;   // wave row offset in tile
    const int wc   = (wave & 1) * 64;    // wave col offset in tile
    const int fr   = lane & 15;
    const int fq   = lane >> 4;          // 0..3

    // rows are 32 bf16 = 4 chunks of 16B; store chunk c at pos (c&3)^(row&3)
#define STAGE(BUF, IT)                                                         \
    {                                                                          \
        const int k0s = kb * DIM + (IT) * BK;                                  \
        {                                                                      \
            int row = t >> 2;                                                  \
            int ks = k0s + (((t & 3) ^ (row & 3)) << 3);                       \
            __builtin_amdgcn_global_load_lds(                                  \
                (const __attribute__((address_space(1))) void*)                \
                    (X + (size_t)(row0 + row) * KDIM + ks),                    \
                (__attribute__((address_space(3))) void*)(&As[BUF][t * 8]),    \
                16, 0, 0);                                                     \
        }                                                                      \
        _Pragma("unroll")                                                      \
        for (int s = 0; s < 2; ++s) {                                          \
            int c = t + s * 256;                                               \
            int row = c >> 2;                                                  \
            int ks = k0s + (((c & 3) ^ (row & 3)) << 3);                       \
            __builtin_amdgcn_global_load_lds(                                  \
                (const __attribute__((address_space(1))) void*)                \
                    (Wc + (size_t)(col0 + row) * KDIM + ks),                   \
                (__attribute__((address_space(3))) void*)(&Bs[BUF][c * 8]),    \
                16, 0, 0);                                                     \
        }                                                                      \
    }

    f32x4 acc[2][4];
#pragma unroll
    for (int i = 0; i < 2; ++i)
#pragma unroll
        for (int j = 0; j < 4; ++j) acc[i][j] = (f32x4){0.f, 0.f, 0.f, 0.f};

    STAGE(0, 0);
    __syncthreads();                     // drains vmcnt(0) + barrier

    int buf = 0;
    for (int it = 0; it < KITERS; ++it) {
        if (it + 1 < KITERS) STAGE(buf ^ 1, it + 1);   // async, overlaps MFMAs

        const ushort* as = As[buf];
        const ushort* bs = Bs[buf];
        const int sw = ((fq ^ (fr & 3)) << 3);         // swizzled k-offset
        bf16x8 a0 = *(const bf16x8*)(as + (wr + fr) * BK + sw);
        bf16x8 a1 = *(const bf16x8*)(as + (wr + 16 + fr) * BK + sw);
#pragma unroll
        for (int j = 0; j < 4; ++j) {
            bf16x8 bv = *(const bf16x8*)(bs + (wc + j * 16 + fr) * BK + sw);
            acc[0][j] = MFMA(a0, bv, acc[0][j]);
            acc[1][j] = MFMA(a1, bv, acc[1][j]);
        }
        __syncthreads();                 // next-tile DMA drained; reads done
        buf ^= 1;
    }

    // epilogue: raw partial -> Y[kb]  (bias/relu/deg applied in ln_kernel)
    ushort* Yk = Y + (size_t)kb * N_PAD * DIM;
#pragma unroll
    for (int i = 0; i < 2; ++i) {
#pragma unroll
        for (int r = 0; r < 4; ++r) {
            int gr = row0 + wr + i * 16 + fq * 4 + r;
            ushort* yrow = Yk + (size_t)gr * DIM;
#pragma unroll
            for (int j = 0; j < 4; ++j) {
                int gc = col0 + wc + j * 16 + fr;
                yrow[gc] = f2bf(acc[i][j][r]);
            }
        }
    }
}

// ---------------------------------------------------------------------------
// LayerNorm: out = LN( bf16(h) + relu(Y0 + Y1 + bself + (deg>0)*bneigh) ).
// 2 rows per 512-thread block; 5000 blocks cover 10000 rows exactly.
// ---------------------------------------------------------------------------
__global__ __launch_bounds__(512) void ln_kernel(
    const ushort* __restrict__ Y, const ushort* __restrict__ Xl,
    const float* __restrict__ deg,
    const float* __restrict__ bself, const float* __restrict__ bneigh,
    const float* __restrict__ g, const float* __restrict__ b,
    float* __restrict__ out)
{
    __shared__ float red[2][8];
    const int half = threadIdx.x >> 8;        // row within block: 0..1
    const int t    = threadIdx.x & 255;       // 0..255, 2 cols each
    const int n    = blockIdx.x * 2 + half;   // 5000*2 = 10000 exact

    float hb = (deg[n] > 0.0f) ? 1.0f : 0.0f;
    ushort2 y0 = *(const ushort2*)(Y + (size_t)n * DIM + t * 2);
    ushort2 y1 = *(const ushort2*)(Y + (size_t)(N_PAD + n) * DIM + t * 2);
    ushort2 xv = *(const ushort2*)(Xl + (size_t)n * KDIM + t * 2);
    float2 bsv = *(const float2*)(bself + t * 2);
    float2 bnv = *(const float2*)(bneigh + t * 2);
    float v0 = b2f(xv.x) + fmaxf(b2f(y0.x) + b2f(y1.x) + bsv.x + hb * bnv.x, 0.f);
    float v1 = b2f(xv.y) + fmaxf(b2f(y0.y) + b2f(y1.y) + bsv.y + hb * bnv.y, 0.f);
    float s  = v0 + v1;
    float sq = v0 * v0 + v1 * v1;
#pragma unroll
    for (int off = 32; off >= 1; off >>= 1) {
        s  += __shfl_xor(s, off);
        sq += __shfl_xor(sq, off);
    }
    int wave = t >> 6;                        // wave within this row: 0..3
    if ((t & 63) == 0) { red[half][wave] = s; red[half][4 + wave] = sq; }
    __syncthreads();
    s  = red[half][0] + red[half][1] + red[half][2] + red[half][3];
    sq = red[half][4] + red[half][5] + red[half][6] + red[half][7];
    float mean = s * (1.0f / DIM);
    float var  = sq * (1.0f / DIM) - mean * mean;
    float rstd = rsqrtf(var + 1e-5f);
    float2 gv = *(const float2*)(g + t * 2);
    float2 bv = *(const float2*)(b + t * 2);
    float2 o;
    o.x = (v0 - mean) * rstd * gv.x + bv.x;
    o.y = (v1 - mean) * rstd * gv.y + bv.y;
    *(float2*)(out + (size_t)n * DIM + t * 2) = o;
}

// ---------------------------------------------------------------------------
extern "C" void kernel_launch(void* const* d_in, const int* in_sizes, int n_in,
                              void* d_out, int out_size, void* d_ws, size_t ws_size,
                              hipStream_t stream)
{
    const float* h      = (const float*)d_in[0];
    const int*   eidx   = (const int*)d_in[1];
    const float* Wself  = (const float*)d_in[2];
    const float* bself  = (const float*)d_in[3];
    const float* Wneigh = (const float*)d_in[4];
    const float* bneigh = (const float*)d_in[5];
    const float* gamma  = (const float*)d_in[6];
    const float* beta   = (const float*)d_in[7];
    float* out = (float*)d_out;

    // ws: X (20.6MB) | Wc (1MB) | Y (2 x 10.3MB) | deg | cnt | col | H8 (5.1MB)
    ushort* X   = (ushort*)d_ws;                          // N_PAD*KDIM bf16
    ushort* Wc  = X + (size_t)N_PAD * KDIM;               // 512*KDIM bf16
    ushort* Y   = Wc + (size_t)DIM * KDIM;                // 2*N_PAD*DIM bf16
    float* deg  = (float*)(Y + (size_t)2 * N_PAD * DIM);  // N f32
    int* cnt    = (int*)(deg + N_NODES);                  // N int
    int* col    = cnt + N_NODES;                          // N*CAP int (2.56MB)
    unsigned char* H8 = (unsigned char*)(col + (size_t)N_NODES * CAP);  // N*DIM fp8

    hipMemsetAsync(cnt, 0, N_NODES * sizeof(int), stream);

    conv_all<<<(N_PAD * 128) / 256, 256, 0, stream>>>(
        Wself, Wneigh, Wc, h, X, H8, eidx, cnt, col);

    gather_agg<<<(N_NODES * 64) / 256, 256, 0, stream>>>(cnt, col, H8, X, deg);

    mfma_gemm<<<NWG, 256, 0, stream>>>(X, Wc, Y);

    ln_kernel<<<N_NODES / 2, 512, 0, stream>>>(Y, X, deg, bself, bneigh,
                                               gamma, beta, out);
}